// Round 17
// baseline (202.357 us; speedup 1.0000x reference)
//
#include <hip/hip_runtime.h>
#include <hip/hip_bf16.h>

#define B 16
#define V 1024
#define D 16
#define E 64
#define F 16
#define H 128
#define HD 64
#define BV (B*V)      // 16384
#define BVD (B*V*D)   // 262144

// ---- workspace layout (float offsets) ----
#define OFF_HNB      0
#define OFF_NORM     (OFF_HNB + BV*H/2)
#define OFF_DV       (OFF_NORM + BVD)
#define OFF_WT       (OFF_DV + BV)
#define OFF_WTG      (OFF_WT + 65536)
#define OFF_WPQ      (OFF_WTG + 8192)
#define OFF_WU1T     (OFF_WPQ + 8192)
#define OFF_WENCT    (OFF_WU1T + 4096)

typedef __attribute__((ext_vector_type(8))) short bf16x8;
typedef __attribute__((ext_vector_type(4))) float f32x4;

__device__ __forceinline__ short f2bf(float f){
  __hip_bfloat16 b = __float2bfloat16(f);
  return *reinterpret_cast<short*>(&b);
}
__device__ __forceinline__ float bf2f(short s){
  __hip_bfloat16 b; *reinterpret_cast<short*>(&b) = s;
  return __bfloat162float(b);
}
__device__ __forceinline__ float frcp(float x){ return __builtin_amdgcn_rcpf(x); }
__device__ __forceinline__ float fsig(float x){ return frcp(1.f + __expf(-x)); }
__device__ __forceinline__ float ftanh(float x){
  float e = __expf(-2.f*fabsf(x));
  float r = (1.f - e)*frcp(1.f + e);
  return copysignf(r, x);
}

// ---- weight packs only ----
__global__ __launch_bounds__(256) void k_pre(const float* __restrict__ Wx, const float* __restrict__ Wh,
    const float* __restrict__ Wg, const float* __restrict__ W1, const float* __restrict__ Wu1,
    const float* __restrict__ Wenc,
    short* __restrict__ Wt, short* __restrict__ Wgt, short* __restrict__ Wpq,
    short* __restrict__ Wu1t, short* __restrict__ Wenct){
  int bid = blockIdx.x, tid = threadIdx.x;
  if (bid < 512){
    int n = bid, k = tid;
    int g = n >> 7, j = n & 127;
    float v;
    if (g == 0)      v = (k < 128) ? Wx[k*384 + j]       : Wh[(k-128)*384 + j];
    else if (g == 1) v = (k < 128) ? Wx[k*384 + 128 + j] : Wh[(k-128)*384 + 128 + j];
    else if (g == 2) v = (k < 128) ? Wx[k*384 + 256 + j] : 0.f;
    else             v = (k < 128) ? 0.f                 : Wh[(k-128)*384 + 256 + j];
    Wt[n*256 + k] = f2bf(v);
    return;
  }
  if (bid < 576){
    int idx = (bid-512)*256 + tid;
    int n = idx >> 7, k = idx & 127;
    Wgt[n*128 + k] = f2bf(Wg[k*128 + n]);
    return;
  }
  if (bid < 608){
    int idx = (bid-576)*256 + tid;
    int n = idx >> 7, k = idx & 127;
    float wb = W1[(k+128)*HD + n];
    float wa = W1[k*HD + n];
    Wpq[n*128 + k]      = f2bf(wa + wb);
    Wpq[(64+n)*128 + k] = f2bf(wb);
    return;
  }
  if (bid < 640){
    int idx = (bid-608)*256 + tid;
    int n = idx >> 7, k = idx & 127;
    Wu1t[n*128 + k] = f2bf(Wu1[k*HD + n]);
    return;
  }
  {
    int nn = (bid-640)*2 + (tid >> 7);
    int kk = tid & 127;
    if (kk < 96) Wenct[nn*96 + kk] = f2bf(kk < 80 ? Wenc[kk*128 + nn] : 0.f);
  }
}

// MEGA: per 64-node tile (+16 halo), 1024 threads (16 waves).
__global__ __launch_bounds__(1024,4) void k_mega(const float* __restrict__ emb, const float* __restrict__ nf,
    const short* __restrict__ Wenct, const float* __restrict__ benc, const int* __restrict__ adj,
    const short* __restrict__ Wgt, const float* __restrict__ bg, const float* __restrict__ ag,
    const short* __restrict__ Wt, const float* __restrict__ bgru, short* __restrict__ hout){
  __shared__ short NE[96][136];
  __shared__ short T[96][136];
  __shared__ short H1[80][136];
  __shared__ short X[80][136];
  __shared__ float Lp[16][96];
  __shared__ float Ls[96];
  __shared__ float nrmv[96];
  short (*As)[104] = reinterpret_cast<short(*)[104]>(&H1[0][0]);  // enc staging overlay

  int tid = threadIdx.x;
  int blk = blockIdx.x;
  int b = blk >> 4;
  int n0 = (blk & 15) << 6;
  int w = tid >> 6, lane = tid & 63;
  int l15 = lane & 15, quad = lane >> 4;
  int ng = w & 7, mh = w >> 3;

  // ---- E1: emb norms ----
  if (tid < 96){
    int v = (n0 - 16 + tid) & 1023;
    const float4* e4 = reinterpret_cast<const float4*>(&emb[v*E]);
    float ss = 0.f;
    #pragma unroll
    for (int q=0;q<16;q++){ float4 x = e4[q]; ss += x.x*x.x + x.y*x.y + x.z*x.z + x.w*x.w; }
    nrmv[tid] = frcp(fmaxf(sqrtf(ss), 1.f));
  }
  __syncthreads();
  // ---- E2: stage As[96][96] bf16 ----
  for (int e=tid; e<96*16; e+=1024){
    int r = e >> 4, q = e & 15;
    int v = (n0 - 16 + r) & 1023;
    float4 x = reinterpret_cast<const float4*>(&emb[v*E])[q];
    float iv = nrmv[r];
    short4 s; s.x=f2bf(x.x*iv); s.y=f2bf(x.y*iv); s.z=f2bf(x.z*iv); s.w=f2bf(x.w*iv);
    *reinterpret_cast<short4*>(&As[r][q*4]) = s;
  }
  if (tid < 96*4){
    int r = tid >> 2, q = tid & 3;
    int m = (b<<10) + ((n0 - 16 + r) & 1023);
    float4 x = reinterpret_cast<const float4*>(&nf[(long)m*F])[q];
    short4 s; s.x=f2bf(x.x); s.y=f2bf(x.y); s.z=f2bf(x.z); s.w=f2bf(x.w);
    *reinterpret_cast<short4*>(&As[r][64 + q*4]) = s;
    short4 z; z.x=0; z.y=0; z.z=0; z.w=0;
    *reinterpret_cast<short4*>(&As[r][80 + q*4]) = z;
  }
  __syncthreads();
  // ---- E3: encoder MFMA (96x128, K=96) ----
  {
    f32x4 acc[3];
    #pragma unroll
    for (int i=0;i<3;i++) acc[i] = (f32x4){0.f,0.f,0.f,0.f};
    #pragma unroll
    for (int kc=0;kc<3;kc++){
      int k0 = kc*32;
      bf16x8 bfr = *reinterpret_cast<const bf16x8*>(&Wenct[(16*ng + l15)*96 + k0 + quad*8]);
      #pragma unroll
      for (int i=0;i<3;i++){
        bf16x8 a = *reinterpret_cast<const bf16x8*>(&As[16*(3*mh+i) + l15][k0 + quad*8]);
        acc[i] = __builtin_amdgcn_mfma_f32_16x16x32_bf16(a, bfr, acc[i], 0,0,0);
      }
    }
    int c = 16*ng + l15;
    float bb = benc[c];
    #pragma unroll
    for (int i=0;i<3;i++)
      #pragma unroll
      for (int reg=0;reg<4;reg++)
        NE[16*(3*mh+i) + quad*4 + reg][c] = f2bf(acc[i][reg] + bb);
  }
  __syncthreads();
  // ---- P1: GAT-1 t + logits for 96 rows ----
  {
    f32x4 acc[3];
    #pragma unroll
    for (int i=0;i<3;i++) acc[i] = (f32x4){0.f,0.f,0.f,0.f};
    #pragma unroll
    for (int kc=0;kc<4;kc++){
      int k0 = kc*32;
      bf16x8 bfr = *reinterpret_cast<const bf16x8*>(&Wgt[(16*ng + l15)*128 + k0 + quad*8]);
      #pragma unroll
      for (int i=0;i<3;i++){
        bf16x8 a = *reinterpret_cast<const bf16x8*>(&NE[16*(3*mh+i) + l15][k0 + quad*8]);
        acc[i] = __builtin_amdgcn_mfma_f32_16x16x32_bf16(a, bfr, acc[i], 0,0,0);
      }
    }
    int c = 16*ng + l15;
    float bgc = bg[c], agc = ag[c];
    float lp[3][4];
    #pragma unroll
    for (int i=0;i<3;i++)
      #pragma unroll
      for (int reg=0;reg<4;reg++){
        float t = ftanh(acc[i][reg] + bgc);
        T[16*(3*mh+i) + quad*4 + reg][c] = f2bf(t);
        lp[i][reg] = t * agc;
      }
    #pragma unroll
    for (int i=0;i<3;i++)
      #pragma unroll
      for (int reg=0;reg<4;reg++){
        lp[i][reg] += __shfl_xor(lp[i][reg], 1);
        lp[i][reg] += __shfl_xor(lp[i][reg], 2);
        lp[i][reg] += __shfl_xor(lp[i][reg], 4);
        lp[i][reg] += __shfl_xor(lp[i][reg], 8);
      }
    if (l15 == 0){
      #pragma unroll
      for (int i=0;i<3;i++)
        #pragma unroll
        for (int reg=0;reg<4;reg++)
          Lp[w][16*(3*mh+i) + quad*4 + reg] = lp[i][reg];
    }
  }
  __syncthreads();
  // FIX: row r's logit partials live only in its m-half's 8 waves (boundary row 48)
  if (tid < 96){
    int base = (tid < 48) ? 0 : 8;
    float s = 0.f;
    #pragma unroll
    for (int i=0;i<8;i++) s += Lp[base + i][tid];
    Ls[tid] = s;
  }
  __syncthreads();
  // ---- P2: msg1 + x1 for 80 rows -> X[0..80) ----
  if (tid < 640){
    int vl = tid >> 3, seg = tid & 7;
    int wg = (b<<10) + ((n0 - 8 + vl) & 1023);
    int li[16]; float at[16];
    float m = -1e30f;
    #pragma unroll
    for (int d=0; d<16; d++){
      int a = adj[wg*16 + d];
      li[d] = (a - n0 + 16) & 1023;
      m = fmaxf(m, Ls[li[d]]);
    }
    float s = 0.f;
    #pragma unroll
    for (int d=0; d<16; d++){ at[d] = __expf(Ls[li[d]] - m); s += at[d]; }
    float inv = frcp(s);
    #pragma unroll
    for (int d=0; d<16; d++) at[d] *= inv;
    #pragma unroll
    for (int c8=0; c8<2; c8++){
      int c = seg*16 + c8*8;
      float acc8[8] = {0,0,0,0,0,0,0,0};
      #pragma unroll 4
      for (int d=0; d<16; d++){
        bf16x8 tv = *reinterpret_cast<const bf16x8*>(&T[li[d]][c]);
        float a = at[d];
        #pragma unroll
        for (int q=0;q<8;q++) acc8[q] += a * bf2f(tv[q]);
      }
      bf16x8 nv = *reinterpret_cast<const bf16x8*>(&NE[vl + 8][c]);
      bf16x8 xv;
      #pragma unroll
      for (int q=0;q<8;q++) xv[q] = f2bf(ftanh(acc8[q] + bf2f(nv[q])));
      *reinterpret_cast<bf16x8*>(&X[vl][c]) = xv;
    }
  }
  __syncthreads();
  // ---- P3: GRU-1 for 80 rows ----
  {
    int first = mh ? 3 : 0, cnt = mh ? 2 : 3;
    f32x4 acc[3][4];
    #pragma unroll
    for (int i=0;i<3;i++)
      #pragma unroll
      for (int g=0;g<4;g++) acc[i][g] = (f32x4){0.f,0.f,0.f,0.f};
    for (int k8=0;k8<8;k8++){
      int k0 = k8*32;
      int gg = (k8 < 4) ? 2 : 3;
      int ncol = 16*ng + l15;
      int koff = k0 + quad*8;
      bf16x8 bz = *reinterpret_cast<const bf16x8*>(&Wt[(ncol      )*256 + koff]);
      bf16x8 br = *reinterpret_cast<const bf16x8*>(&Wt[(ncol + 128)*256 + koff]);
      bf16x8 bc = *reinterpret_cast<const bf16x8*>(&Wt[(ncol + gg*128)*256 + koff]);
      #pragma unroll
      for (int i=0;i<3;i++){
        if (i < cnt){
          int mt = first + i;
          bf16x8 a;
          if (k8 < 4) a = *reinterpret_cast<const bf16x8*>(&X[16*mt + l15][k0 + quad*8]);
          else        a = *reinterpret_cast<const bf16x8*>(&NE[16*mt + l15 + 8][k0 - 128 + quad*8]);
          acc[i][0]  = __builtin_amdgcn_mfma_f32_16x16x32_bf16(a, bz, acc[i][0], 0,0,0);
          acc[i][1]  = __builtin_amdgcn_mfma_f32_16x16x32_bf16(a, br, acc[i][1], 0,0,0);
          acc[i][gg] = __builtin_amdgcn_mfma_f32_16x16x32_bf16(a, bc, acc[i][gg], 0,0,0);
        }
      }
    }
    int j = 16*ng + l15;
    float bjz = bgru[j], bjr = bgru[128 + j], bjc = bgru[256 + j];
    #pragma unroll
    for (int i=0;i<3;i++){
      if (i < cnt){
        int mt = first + i;
        #pragma unroll
        for (int reg=0;reg<4;reg++){
          int rl = 16*mt + quad*4 + reg;
          float z = fsig(acc[i][0][reg] + bjz);
          float r = fsig(acc[i][1][reg] + bjr);
          float cand = ftanh(acc[i][2][reg] + bjc + r*acc[i][3][reg]);
          float ho = bf2f(NE[rl + 8][j]);
          H1[rl][j] = f2bf(z*ho + (1.f - z)*cand);
        }
      }
    }
  }
  __syncthreads();
  // ---- P4: GAT-2 t + logits for 80 rows ----
  {
    int first = mh ? 3 : 0, cnt = mh ? 2 : 3;
    f32x4 acc[3];
    #pragma unroll
    for (int i=0;i<3;i++) acc[i] = (f32x4){0.f,0.f,0.f,0.f};
    #pragma unroll
    for (int kc=0;kc<4;kc++){
      int k0 = kc*32;
      bf16x8 bfr = *reinterpret_cast<const bf16x8*>(&Wgt[(16*ng + l15)*128 + k0 + quad*8]);
      #pragma unroll
      for (int i=0;i<3;i++){
        if (i < cnt){
          bf16x8 a = *reinterpret_cast<const bf16x8*>(&H1[16*(first+i) + l15][k0 + quad*8]);
          acc[i] = __builtin_amdgcn_mfma_f32_16x16x32_bf16(a, bfr, acc[i], 0,0,0);
        }
      }
    }
    int c = 16*ng + l15;
    float bgc = bg[c], agc = ag[c];
    float lp[3][4];
    #pragma unroll
    for (int i=0;i<3;i++){
      if (i < cnt){
        #pragma unroll
        for (int reg=0;reg<4;reg++){
          float t = ftanh(acc[i][reg] + bgc);
          T[16*(first+i) + quad*4 + reg][c] = f2bf(t);
          lp[i][reg] = t * agc;
        }
      }
    }
    #pragma unroll
    for (int i=0;i<3;i++){
      if (i < cnt){
        #pragma unroll
        for (int reg=0;reg<4;reg++){
          lp[i][reg] += __shfl_xor(lp[i][reg], 1);
          lp[i][reg] += __shfl_xor(lp[i][reg], 2);
          lp[i][reg] += __shfl_xor(lp[i][reg], 4);
          lp[i][reg] += __shfl_xor(lp[i][reg], 8);
        }
      }
    }
    if (l15 == 0){
      #pragma unroll
      for (int i=0;i<3;i++){
        if (i < cnt){
          #pragma unroll
          for (int reg=0;reg<4;reg++)
            Lp[w][16*(first+i) + quad*4 + reg] = lp[i][reg];
        }
      }
    }
  }
  __syncthreads();
  // FIX: boundary row 48 (mh0: tiles 0-2 = rows 0..48, mh1: tiles 3-4 = rows 48..80)
  if (tid < 80){
    int base = (tid < 48) ? 0 : 8;
    float s = 0.f;
    #pragma unroll
    for (int i=0;i<8;i++) s += Lp[base + i][tid];
    Ls[tid] = s;
  }
  __syncthreads();
  // ---- P5: msg2 + x2 for 64 owned -> X[0..64) ----
  if (tid < 512){
    int vl = tid >> 3, seg = tid & 7;
    int vg = (b<<10) + n0 + vl;
    int li[16]; float at[16];
    float m = -1e30f;
    #pragma unroll
    for (int d=0; d<16; d++){
      int a = adj[vg*16 + d];
      li[d] = (a - n0 + 8) & 1023;
      m = fmaxf(m, Ls[li[d]]);
    }
    float s = 0.f;
    #pragma unroll
    for (int d=0; d<16; d++){ at[d] = __expf(Ls[li[d]] - m); s += at[d]; }
    float inv = frcp(s);
    #pragma unroll
    for (int d=0; d<16; d++) at[d] *= inv;
    #pragma unroll
    for (int c8=0; c8<2; c8++){
      int c = seg*16 + c8*8;
      float acc8[8] = {0,0,0,0,0,0,0,0};
      #pragma unroll 4
      for (int d=0; d<16; d++){
        bf16x8 tv = *reinterpret_cast<const bf16x8*>(&T[li[d]][c]);
        float a = at[d];
        #pragma unroll
        for (int q=0;q<8;q++) acc8[q] += a * bf2f(tv[q]);
      }
      bf16x8 nv = *reinterpret_cast<const bf16x8*>(&NE[vl + 16][c]);
      bf16x8 xv;
      #pragma unroll
      for (int q=0;q<8;q++) xv[q] = f2bf(ftanh(acc8[q] + bf2f(nv[q])));
      *reinterpret_cast<bf16x8*>(&X[vl][c]) = xv;
    }
  }
  __syncthreads();
  // ---- P6: GRU-2 for 64 owned ----
  {
    int first = mh ? 2 : 0;
    f32x4 acc[2][4];
    #pragma unroll
    for (int i=0;i<2;i++)
      #pragma unroll
      for (int g=0;g<4;g++) acc[i][g] = (f32x4){0.f,0.f,0.f,0.f};
    for (int k8=0;k8<8;k8++){
      int k0 = k8*32;
      int gg = (k8 < 4) ? 2 : 3;
      int ncol = 16*ng + l15;
      int koff = k0 + quad*8;
      bf16x8 bz = *reinterpret_cast<const bf16x8*>(&Wt[(ncol      )*256 + koff]);
      bf16x8 br = *reinterpret_cast<const bf16x8*>(&Wt[(ncol + 128)*256 + koff]);
      bf16x8 bc = *reinterpret_cast<const bf16x8*>(&Wt[(ncol + gg*128)*256 + koff]);
      #pragma unroll
      for (int i=0;i<2;i++){
        int mt = first + i;
        bf16x8 a;
        if (k8 < 4) a = *reinterpret_cast<const bf16x8*>(&X[16*mt + l15][k0 + quad*8]);
        else        a = *reinterpret_cast<const bf16x8*>(&H1[16*mt + l15 + 8][k0 - 128 + quad*8]);
        acc[i][0]  = __builtin_amdgcn_mfma_f32_16x16x32_bf16(a, bz, acc[i][0], 0,0,0);
        acc[i][1]  = __builtin_amdgcn_mfma_f32_16x16x32_bf16(a, br, acc[i][1], 0,0,0);
        acc[i][gg] = __builtin_amdgcn_mfma_f32_16x16x32_bf16(a, bc, acc[i][gg], 0,0,0);
      }
    }
    __syncthreads();
    int j = 16*ng + l15;
    float bjz = bgru[j], bjr = bgru[128 + j], bjc = bgru[256 + j];
    #pragma unroll
    for (int i=0;i<2;i++){
      int mt = first + i;
      #pragma unroll
      for (int reg=0;reg<4;reg++){
        int rl = 16*mt + quad*4 + reg;
        float z = fsig(acc[i][0][reg] + bjz);
        float r = fsig(acc[i][1][reg] + bjr);
        float cand = ftanh(acc[i][2][reg] + bjc + r*acc[i][3][reg]);
        float ho = bf2f(H1[rl + 8][j]);
        X[rl][j] = f2bf(z*ho + (1.f - z)*cand);
      }
    }
  }
  __syncthreads();
  if (tid < 64*16){
    int r = tid >> 4, c8 = tid & 15;
    *reinterpret_cast<bf16x8*>(&hout[(long)((b<<10) + n0 + r)*128 + c8*8]) =
        *reinterpret_cast<const bf16x8*>(&X[r][c8*8]);
  }
}

// Fused decoder + dest-attn + sparsemax + dual-vars, 512 threads.
__global__ __launch_bounds__(512,2) void k_decdas(const short* __restrict__ hn, const int* __restrict__ adj,
    const int* __restrict__ invadj, const short* __restrict__ Wpq, const float* __restrict__ b1,
    const float* __restrict__ W2, const float* __restrict__ b2_,
    const short* __restrict__ Wu1t, const float* __restrict__ bu1, const float* __restrict__ Wu2,
    const float* __restrict__ bu2_, float* __restrict__ norm_, float* __restrict__ dv){
  __shared__ short Hs[112][136];
  __shared__ short PQb[112][132];
  __shared__ short NSs[64][136];
  __shared__ int adjL[64][16];
  __shared__ float dvp[64][4];
  __shared__ float b1s[64], w2s[64], bu1s[64], wu2s[64];
  int tid = threadIdx.x;
  int blk = blockIdx.x;
  int b = blk >> 4;
  int n0 = (blk & 15) << 6;
  if (tid < 64){ b1s[tid] = b1[tid]; w2s[tid] = W2[tid]; bu1s[tid] = bu1[tid]; wu2s[tid] = Wu2[tid]; }
  for (int idx=tid; idx<112*16; idx+=512){
    int r = idx >> 4, c8 = idx & 15;
    int g = (b << 10) + ((n0 - 24 + r) & 1023);
    *reinterpret_cast<bf16x8*>(&Hs[r][c8*8]) =
        *reinterpret_cast<const bf16x8*>(&hn[(long)g*128 + c8*8]);
  }
  for (int idx=tid; idx<1024; idx+=512){
    int r = idx >> 4, d = idx & 15;
    int a = adj[((b<<10) + n0 + r)*16 + d];
    adjL[r][d] = (a - n0 + 24) & 1023;
  }
  __syncthreads();
  int w = tid >> 6, lane = tid & 63;
  int l15 = lane & 15, quad = lane >> 4;
  {
    f32x4 acc[7];
    #pragma unroll
    for (int mt=0;mt<7;mt++) acc[mt] = (f32x4){0.f,0.f,0.f,0.f};
    #pragma unroll
    for (int kc=0;kc<4;kc++){
      int k0 = kc*32;
      bf16x8 bfr = *reinterpret_cast<const bf16x8*>(&Wpq[(16*w + l15)*128 + k0 + quad*8]);
      #pragma unroll
      for (int mt=0;mt<7;mt++){
        bf16x8 a = *reinterpret_cast<const bf16x8*>(&Hs[16*mt + l15][k0 + quad*8]);
        acc[mt] = __builtin_amdgcn_mfma_f32_16x16x32_bf16(a, bfr, acc[mt], 0,0,0);
      }
    }
    int c = 16*w + l15;
    #pragma unroll
    for (int mt=0;mt<7;mt++)
      #pragma unroll
      for (int reg=0;reg<4;reg++)
        PQb[16*mt + quad*4 + reg][c] = f2bf(acc[mt][reg]);
  }
  for (int idx=tid; idx<64*16; idx+=512){
    int r = idx >> 4, c8 = idx & 15;
    float acc8[8] = {0,0,0,0,0,0,0,0};
    #pragma unroll 4
    for (int d=0; d<16; d++){
      bf16x8 hv = *reinterpret_cast<const bf16x8*>(&Hs[adjL[r][d]][c8*8]);
      #pragma unroll
      for (int q=0;q<8;q++) acc8[q] += bf2f(hv[q]);
    }
    bf16x8 sv;
    #pragma unroll
    for (int q=0;q<8;q++) sv[q] = f2bf(acc8[q]);
    *reinterpret_cast<bf16x8*>(&NSs[r][c8*8]) = sv;
  }
  __syncthreads();
  if (w < 4){
    f32x4 acc[4];
    #pragma unroll
    for (int mt=0;mt<4;mt++) acc[mt] = (f32x4){0.f,0.f,0.f,0.f};
    #pragma unroll
    for (int kc=0;kc<4;kc++){
      int k0 = kc*32;
      bf16x8 bfr = *reinterpret_cast<const bf16x8*>(&Wu1t[(16*w + l15)*128 + k0 + quad*8]);
      #pragma unroll
      for (int mt=0;mt<4;mt++){
        bf16x8 a = *reinterpret_cast<const bf16x8*>(&NSs[16*mt + l15][k0 + quad*8]);
        acc[mt] = __builtin_amdgcn_mfma_f32_16x16x32_bf16(a, bfr, acc[mt], 0,0,0);
      }
    }
    int n = 16*w + l15;
    float bn = bu1s[n], wn = wu2s[n];
    #pragma unroll
    for (int mt=0;mt<4;mt++){
      #pragma unroll
      for (int reg=0;reg<4;reg++){
        float p = ftanh(acc[mt][reg] + bn) * wn;
        p += __shfl_xor(p, 1);
        p += __shfl_xor(p, 2);
        p += __shfl_xor(p, 4);
        p += __shfl_xor(p, 8);
        if (l15 == 0) dvp[16*mt + quad*4 + reg][w] = p;
      }
    }
  }
  __syncthreads();
  float* nws = reinterpret_cast<float*>(&Hs[0][0]);   // [96][17]
  float b2v = b2_[0];
  for (int e = tid; e < 96*16; e += 512){
    int rr = e >> 4, d = e & 15;
    int wnode = (n0 + rr - 16) & 1023;
    int wg = (b<<10) + wnode;
    int a = adj[wg*16 + d];
    int al = (a - n0 + 24) & 1023;
    int wl = rr + 8;
    float p = 0.f;
    #pragma unroll 8
    for (int c=0;c<64;c++)
      p += ftanh(bf2f(PQb[al][c]) + bf2f(PQb[wl][64 + c]) + b1s[c]) * w2s[c];
    nws[rr*17 + d] = p + b2v;
  }
  __syncthreads();
  if (tid < 64){
    float val = dvp[tid][0]+dvp[tid][1]+dvp[tid][2]+dvp[tid][3];
    dv[(b<<10) + n0 + tid] = fmaxf(val + bu2_[0], 0.f);
  }
  float* datt = reinterpret_cast<float*>(&PQb[0][0]); // [80][17]
  if (tid < 80){
    int wnode = (n0 + tid - 8) & 1023;
    int wg = (b<<10) + wnode;
    float vals[16];
    float m = -1e30f;
    #pragma unroll
    for (int d=0; d<16; d++){
      int iv = invadj[wg*16 + d];
      int il = (iv - n0 + 16) & 1023;
      vals[d] = nws[il*17 + d];
      m = fmaxf(m, vals[d]);
    }
    float s = 0.f;
    #pragma unroll
    for (int d=0; d<16; d++){ vals[d] = __expf(vals[d]-m); s += vals[d]; }
    float inv = frcp(s);
    #pragma unroll
    for (int d=0; d<16; d++) datt[tid*17 + d] = vals[d]*inv;
  }
  __syncthreads();
  if (tid < 64){
    int vg = (b<<10) + n0 + tid;
    float z[16], s[16];
    #pragma unroll
    for (int d=0; d<16; d++){
      int al = adjL[tid][d] - 16;
      z[d] = datt[al*17 + d];
      s[d] = z[d];
    }
    #pragma unroll
    for (int k2 = 2; k2 <= 16; k2 <<= 1){
      #pragma unroll
      for (int jj = k2 >> 1; jj > 0; jj >>= 1){
        #pragma unroll
        for (int i = 0; i < 16; i++){
          int l = i ^ jj;
          if (l > i){
            bool up = ((i & k2) == 0);
            float a = s[i], bb = s[l];
            bool sw = up ? (a > bb) : (a < bb);
            if (sw){ s[i]=bb; s[l]=a; }
          }
        }
      }
    }
    float cs = 0.f, zcs = 0.f; int kz = 1;
    #pragma unroll
    for (int j=0;j<16;j++){
      float zj = s[15-j];
      cs += zj;
      if (1.f + (float)(j+1)*zj > cs){ kz = j+1; zcs = cs; }
    }
    float tau = (zcs - 1.f)/(float)kz;
    #pragma unroll
    for (int d=0; d<16; d++) norm_[(long)vg*16 + d] = fmaxf(z[d]-tau, 0.f);
  }
}

// Fused flow solver + dual cost + dual demand + final output.
__global__ __launch_bounds__(1024) void k_flowfin(const float* __restrict__ norm_,
    const float* __restrict__ dem, const int* __restrict__ invadj, const float* __restrict__ dv,
    float* __restrict__ out){
  __shared__ float nrmS[V*17];
  __shared__ float sbuf[2][V];
  __shared__ float r1[16], r2[16], r3[16];
  int b = blockIdx.x, v = threadIdx.x;
  int gv = (b<<10) + v;
  {
    const float4* src = reinterpret_cast<const float4*>(&norm_[(long)gv*16]);
    #pragma unroll
    for (int q4=0; q4<4; q4++){
      float4 x = src[q4];
      nrmS[v*17 + q4*4+0] = x.x; nrmS[v*17 + q4*4+1] = x.y;
      nrmS[v*17 + q4*4+2] = x.z; nrmS[v*17 + q4*4+3] = x.w;
    }
  }
  int iv[16];
  #pragma unroll
  for (int d4=0; d4<4; d4++){
    int4 i4 = reinterpret_cast<const int4*>(&invadj[(long)gv*16])[d4];
    iv[d4*4+0]=i4.x; iv[d4*4+1]=i4.y; iv[d4*4+2]=i4.z; iv[d4*4+3]=i4.w;
  }
  float dm = dem[gv];
  sbuf[0][v] = 0.f;
  __syncthreads();
  float nrg[16]; float nr2 = 0.f;
  #pragma unroll
  for (int d=0; d<16; d++){
    nrg[d] = nrmS[iv[d]*17 + d];
    float nv = nrmS[v*17 + d];
    nr2 += nv*nv;
  }
  int p = 0;
  float s = 0.f;
  for (int it=0; it<10; it++){
    float inflow = 0.f;
    #pragma unroll
    for (int d=0; d<16; d++) inflow += nrg[d]*sbuf[p][iv[d]];
    s = fmaxf(inflow - dm, 0.f);
    sbuf[1-p][v] = s;
    p ^= 1;
    __syncthreads();
  }
  float partF = nr2 * s * s;
  float dvv = dv[gv];
  float f = 0.f, vel = 0.f;
  #pragma unroll
  for (int it=0; it<10; it++){
    float g = 2.f*f + dvv;
    vel = 0.9f*vel - 0.01f*g;
    f = fmaxf(f + vel, 0.f);
  }
  float partD = f*f + dvv*f;
  float partDD = dvv * dm;
  #pragma unroll
  for (int off=32; off>0; off>>=1){
    partF  += __shfl_down(partF, off);
    partD  += __shfl_down(partD, off);
    partDD += __shfl_down(partDD, off);
  }
  if ((v & 63) == 0){ r1[v>>6] = partF; r2[v>>6] = partD; r3[v>>6] = partDD; }
  __syncthreads();
  if (v == 0){
    float sf = 0.f, sd = 0.f, sdd = 0.f;
    #pragma unroll
    for (int i=0;i<16;i++){ sf += r1[i]; sd += r2[i]; sdd += r3[i]; }
    out[b] = sf - (16.f*sd - sdd);
  }
}

extern "C" void kernel_launch(void* const* d_in, const int* in_sizes, int n_in,
                              void* d_out, int out_size, void* d_ws, size_t ws_size,
                              hipStream_t stream){
  (void)in_sizes; (void)n_in; (void)out_size; (void)ws_size;
  const float* demands = (const float*)d_in[0];
  const float* nf      = (const float*)d_in[1];
  const float* emb     = (const float*)d_in[4];
  const float* Wenc    = (const float*)d_in[5];
  const float* benc    = (const float*)d_in[6];
  const float* Wgat    = (const float*)d_in[7];
  const float* bgat    = (const float*)d_in[8];
  const float* agat    = (const float*)d_in[9];
  const float* Wgx     = (const float*)d_in[10];
  const float* Wgh     = (const float*)d_in[11];
  const float* bgru    = (const float*)d_in[12];
  const float* Wd1     = (const float*)d_in[13];
  const float* bd1     = (const float*)d_in[14];
  const float* Wd2     = (const float*)d_in[15];
  const float* bd2     = (const float*)d_in[16];
  const float* Wu1     = (const float*)d_in[17];
  const float* bu1     = (const float*)d_in[18];
  const float* Wu2     = (const float*)d_in[19];
  const float* bu2     = (const float*)d_in[20];
  const int* adj       = (const int*)d_in[21];
  const int* invadj    = (const int*)d_in[22];

  float* ws    = (float*)d_ws;
  short* hnB   = (short*)(ws + OFF_HNB);
  float* nrm   = ws + OFF_NORM;
  float* dv    = ws + OFF_DV;
  short* wt    = (short*)(ws + OFF_WT);
  short* wtg   = (short*)(ws + OFF_WTG);
  short* wpq   = (short*)(ws + OFF_WPQ);
  short* wu1t  = (short*)(ws + OFF_WU1T);
  short* wenct = (short*)(ws + OFF_WENCT);

  k_pre<<<704, 256, 0, stream>>>(Wgx, Wgh, Wgat, Wd1, Wu1, Wenc, wt, wtg, wpq, wu1t, wenct);
  k_mega<<<BV/64, 1024, 0, stream>>>(emb, nf, wenct, benc, adj, wtg, bgat, agat, wt, bgru, hnB);
  k_decdas<<<BV/64, 512, 0, stream>>>(hnB, adj, invadj, wpq, bd1, Wd2, bd2,
                                      wu1t, bu1, Wu2, bu2, nrm, dv);
  k_flowfin<<<B, 1024, 0, stream>>>(nrm, demands, invadj, dv, (float*)d_out);
}

// Round 18
// 185.047 us; speedup vs baseline: 1.0935x; 1.0935x over previous
//
#include <hip/hip_runtime.h>
#include <hip/hip_bf16.h>

#define B 16
#define V 1024
#define D 16
#define E 64
#define F 16
#define H 128
#define HD 64
#define BV (B*V)      // 16384
#define BVD (B*V*D)   // 262144

// ---- workspace layout (float offsets) ----
#define OFF_HNB      0
#define OFF_NORM     (OFF_HNB + BV*H/2)
#define OFF_DV       (OFF_NORM + BVD)
#define OFF_WT       (OFF_DV + BV)
#define OFF_WTG      (OFF_WT + 65536)
#define OFF_WPQ      (OFF_WTG + 8192)
#define OFF_WU1T     (OFF_WPQ + 8192)
#define OFF_WENCT    (OFF_WU1T + 4096)

typedef __attribute__((ext_vector_type(8))) short bf16x8;
typedef __attribute__((ext_vector_type(4))) float f32x4;

__device__ __forceinline__ short f2bf(float f){
  __hip_bfloat16 b = __float2bfloat16(f);
  return *reinterpret_cast<short*>(&b);
}
__device__ __forceinline__ float bf2f(short s){
  __hip_bfloat16 b; *reinterpret_cast<short*>(&b) = s;
  return __bfloat162float(b);
}
__device__ __forceinline__ float frcp(float x){ return __builtin_amdgcn_rcpf(x); }
__device__ __forceinline__ float fsig(float x){ return frcp(1.f + __expf(-x)); }
__device__ __forceinline__ float ftanh(float x){
  float e = __expf(-2.f*fabsf(x));
  float r = (1.f - e)*frcp(1.f + e);
  return copysignf(r, x);
}

// ---- weight packs only ----
__global__ __launch_bounds__(256) void k_pre(const float* __restrict__ Wx, const float* __restrict__ Wh,
    const float* __restrict__ Wg, const float* __restrict__ W1, const float* __restrict__ Wu1,
    const float* __restrict__ Wenc,
    short* __restrict__ Wt, short* __restrict__ Wgt, short* __restrict__ Wpq,
    short* __restrict__ Wu1t, short* __restrict__ Wenct){
  int bid = blockIdx.x, tid = threadIdx.x;
  if (bid < 512){
    int n = bid, k = tid;
    int g = n >> 7, j = n & 127;
    float v;
    if (g == 0)      v = (k < 128) ? Wx[k*384 + j]       : Wh[(k-128)*384 + j];
    else if (g == 1) v = (k < 128) ? Wx[k*384 + 128 + j] : Wh[(k-128)*384 + 128 + j];
    else if (g == 2) v = (k < 128) ? Wx[k*384 + 256 + j] : 0.f;
    else             v = (k < 128) ? 0.f                 : Wh[(k-128)*384 + 256 + j];
    Wt[n*256 + k] = f2bf(v);
    return;
  }
  if (bid < 576){
    int idx = (bid-512)*256 + tid;
    int n = idx >> 7, k = idx & 127;
    Wgt[n*128 + k] = f2bf(Wg[k*128 + n]);
    return;
  }
  if (bid < 608){
    int idx = (bid-576)*256 + tid;
    int n = idx >> 7, k = idx & 127;
    float wb = W1[(k+128)*HD + n];
    float wa = W1[k*HD + n];
    Wpq[n*128 + k]      = f2bf(wa + wb);
    Wpq[(64+n)*128 + k] = f2bf(wb);
    return;
  }
  if (bid < 640){
    int idx = (bid-608)*256 + tid;
    int n = idx >> 7, k = idx & 127;
    Wu1t[n*128 + k] = f2bf(Wu1[k*HD + n]);
    return;
  }
  {
    int nn = (bid-640)*2 + (tid >> 7);
    int kk = tid & 127;
    if (kk < 96) Wenct[nn*96 + kk] = f2bf(kk < 80 ? Wenc[kk*128 + nn] : 0.f);
  }
}

// MEGA: per 64-node tile (+16 halo), 512 threads (8 waves) — round-14 measured best.
__global__ __launch_bounds__(512,2) void k_mega(const float* __restrict__ emb, const float* __restrict__ nf,
    const short* __restrict__ Wenct, const float* __restrict__ benc, const int* __restrict__ adj,
    const short* __restrict__ Wgt, const float* __restrict__ bg, const float* __restrict__ ag,
    const short* __restrict__ Wt, const float* __restrict__ bgru, short* __restrict__ hout){
  __shared__ short NE[96][136];
  __shared__ short T[96][136];
  __shared__ short H1[80][136];
  __shared__ short X[80][136];
  __shared__ float Lp[8][96];
  __shared__ float Ls[96];
  __shared__ float nrmv[96];
  short (*As)[104] = reinterpret_cast<short(*)[104]>(&H1[0][0]);  // enc staging overlay

  int tid = threadIdx.x;
  int blk = blockIdx.x;
  int b = blk >> 4;
  int n0 = (blk & 15) << 6;
  int w = tid >> 6, lane = tid & 63;
  int l15 = lane & 15, quad = lane >> 4;

  // ---- E1: emb norms for 96 frame rows ----
  if (tid < 96){
    int v = (n0 - 16 + tid) & 1023;
    const float4* e4 = reinterpret_cast<const float4*>(&emb[v*E]);
    float ss = 0.f;
    #pragma unroll
    for (int q=0;q<16;q++){ float4 x = e4[q]; ss += x.x*x.x + x.y*x.y + x.z*x.z + x.w*x.w; }
    nrmv[tid] = frcp(fmaxf(sqrtf(ss), 1.f));
  }
  __syncthreads();
  // ---- E2: stage As[96][96] bf16 ----
  for (int e=tid; e<96*16; e+=512){
    int r = e >> 4, q = e & 15;
    int v = (n0 - 16 + r) & 1023;
    float4 x = reinterpret_cast<const float4*>(&emb[v*E])[q];
    float iv = nrmv[r];
    short4 s; s.x=f2bf(x.x*iv); s.y=f2bf(x.y*iv); s.z=f2bf(x.z*iv); s.w=f2bf(x.w*iv);
    *reinterpret_cast<short4*>(&As[r][q*4]) = s;
  }
  for (int e=tid; e<96*4; e+=512){
    int r = e >> 2, q = e & 3;
    int m = (b<<10) + ((n0 - 16 + r) & 1023);
    float4 x = reinterpret_cast<const float4*>(&nf[(long)m*F])[q];
    short4 s; s.x=f2bf(x.x); s.y=f2bf(x.y); s.z=f2bf(x.z); s.w=f2bf(x.w);
    *reinterpret_cast<short4*>(&As[r][64 + q*4]) = s;
    short4 z; z.x=0; z.y=0; z.z=0; z.w=0;
    *reinterpret_cast<short4*>(&As[r][80 + q*4]) = z;
  }
  __syncthreads();
  // ---- E3: encoder MFMA (96 rows x 128 cols, K=96); wave w owns cols 16w..16w+16 ----
  {
    f32x4 acc[6];
    #pragma unroll
    for (int mt=0;mt<6;mt++) acc[mt] = (f32x4){0.f,0.f,0.f,0.f};
    #pragma unroll
    for (int kc=0;kc<3;kc++){
      int k0 = kc*32;
      bf16x8 bfr = *reinterpret_cast<const bf16x8*>(&Wenct[(16*w + l15)*96 + k0 + quad*8]);
      #pragma unroll
      for (int mt=0;mt<6;mt++){
        bf16x8 a = *reinterpret_cast<const bf16x8*>(&As[16*mt + l15][k0 + quad*8]);
        acc[mt] = __builtin_amdgcn_mfma_f32_16x16x32_bf16(a, bfr, acc[mt], 0,0,0);
      }
    }
    int c = 16*w + l15;
    float bb = benc[c];
    #pragma unroll
    for (int mt=0;mt<6;mt++)
      #pragma unroll
      for (int reg=0;reg<4;reg++)
        NE[16*mt + quad*4 + reg][c] = f2bf(acc[mt][reg] + bb);
  }
  __syncthreads();
  // ---- P1: GAT-1 t + logits for 96 rows ----
  {
    f32x4 acc[6];
    #pragma unroll
    for (int mt=0;mt<6;mt++) acc[mt] = (f32x4){0.f,0.f,0.f,0.f};
    #pragma unroll
    for (int kc=0;kc<4;kc++){
      int k0 = kc*32;
      bf16x8 bfr = *reinterpret_cast<const bf16x8*>(&Wgt[(16*w + l15)*128 + k0 + quad*8]);
      #pragma unroll
      for (int mt=0;mt<6;mt++){
        bf16x8 a = *reinterpret_cast<const bf16x8*>(&NE[16*mt + l15][k0 + quad*8]);
        acc[mt] = __builtin_amdgcn_mfma_f32_16x16x32_bf16(a, bfr, acc[mt], 0,0,0);
      }
    }
    int c = 16*w + l15;
    float bgc = bg[c], agc = ag[c];
    float lp[6][4];
    #pragma unroll
    for (int mt=0;mt<6;mt++)
      #pragma unroll
      for (int reg=0;reg<4;reg++){
        float t = ftanh(acc[mt][reg] + bgc);
        T[16*mt + quad*4 + reg][c] = f2bf(t);
        lp[mt][reg] = t * agc;
      }
    #pragma unroll
    for (int mt=0;mt<6;mt++)
      #pragma unroll
      for (int reg=0;reg<4;reg++){
        lp[mt][reg] += __shfl_xor(lp[mt][reg], 1);
        lp[mt][reg] += __shfl_xor(lp[mt][reg], 2);
        lp[mt][reg] += __shfl_xor(lp[mt][reg], 4);
        lp[mt][reg] += __shfl_xor(lp[mt][reg], 8);
      }
    if (l15 == 0){
      #pragma unroll
      for (int mt=0;mt<6;mt++)
        #pragma unroll
        for (int reg=0;reg<4;reg++)
          Lp[w][16*mt + quad*4 + reg] = lp[mt][reg];
    }
  }
  __syncthreads();
  if (tid < 96){
    float s = 0.f;
    #pragma unroll
    for (int i=0;i<8;i++) s += Lp[i][tid];
    Ls[tid] = s;
  }
  __syncthreads();
  // ---- P2: msg1 + x1 for 80 rows -> X[0..80) ----
  if (tid < 320){
    int vl = tid >> 2, seg = tid & 3;
    int wg = (b<<10) + ((n0 - 8 + vl) & 1023);
    int li[16]; float at[16];
    float m = -1e30f;
    #pragma unroll
    for (int d=0; d<16; d++){
      int a = adj[wg*16 + d];
      li[d] = (a - n0 + 16) & 1023;
      m = fmaxf(m, Ls[li[d]]);
    }
    float s = 0.f;
    #pragma unroll
    for (int d=0; d<16; d++){ at[d] = __expf(Ls[li[d]] - m); s += at[d]; }
    float inv = frcp(s);
    #pragma unroll
    for (int d=0; d<16; d++) at[d] *= inv;
    #pragma unroll
    for (int c8=0; c8<4; c8++){
      int c = seg*32 + c8*8;
      float acc8[8] = {0,0,0,0,0,0,0,0};
      #pragma unroll 4
      for (int d=0; d<16; d++){
        bf16x8 tv = *reinterpret_cast<const bf16x8*>(&T[li[d]][c]);
        float a = at[d];
        #pragma unroll
        for (int q=0;q<8;q++) acc8[q] += a * bf2f(tv[q]);
      }
      bf16x8 nv = *reinterpret_cast<const bf16x8*>(&NE[vl + 8][c]);
      bf16x8 xv;
      #pragma unroll
      for (int q=0;q<8;q++) xv[q] = f2bf(ftanh(acc8[q] + bf2f(nv[q])));
      *reinterpret_cast<bf16x8*>(&X[vl][c]) = xv;
    }
  }
  __syncthreads();
  // ---- P3: GRU-1 for 80 rows: wave w owns gate-col j = 16w+l15 in all groups ----
  {
    f32x4 acc[5][4];
    #pragma unroll
    for (int mt=0;mt<5;mt++)
      #pragma unroll
      for (int g=0;g<4;g++) acc[mt][g] = (f32x4){0.f,0.f,0.f,0.f};
    for (int k8=0;k8<8;k8++){
      int k0 = k8*32;
      int gg = (k8 < 4) ? 2 : 3;
      int ncol = 16*w + l15;
      int koff = k0 + quad*8;
      bf16x8 bz = *reinterpret_cast<const bf16x8*>(&Wt[(ncol      )*256 + koff]);
      bf16x8 br = *reinterpret_cast<const bf16x8*>(&Wt[(ncol + 128)*256 + koff]);
      bf16x8 bc = *reinterpret_cast<const bf16x8*>(&Wt[(ncol + gg*128)*256 + koff]);
      #pragma unroll
      for (int mt=0;mt<5;mt++){
        bf16x8 a;
        if (k8 < 4) a = *reinterpret_cast<const bf16x8*>(&X[16*mt + l15][k0 + quad*8]);
        else        a = *reinterpret_cast<const bf16x8*>(&NE[16*mt + l15 + 8][k0 - 128 + quad*8]);
        acc[mt][0]  = __builtin_amdgcn_mfma_f32_16x16x32_bf16(a, bz, acc[mt][0], 0,0,0);
        acc[mt][1]  = __builtin_amdgcn_mfma_f32_16x16x32_bf16(a, br, acc[mt][1], 0,0,0);
        acc[mt][gg] = __builtin_amdgcn_mfma_f32_16x16x32_bf16(a, bc, acc[mt][gg], 0,0,0);
      }
    }
    int j = 16*w + l15;
    float bjz = bgru[j], bjr = bgru[128 + j], bjc = bgru[256 + j];
    #pragma unroll
    for (int mt=0;mt<5;mt++){
      #pragma unroll
      for (int reg=0;reg<4;reg++){
        int rl = 16*mt + quad*4 + reg;
        float z = fsig(acc[mt][0][reg] + bjz);
        float r = fsig(acc[mt][1][reg] + bjr);
        float cand = ftanh(acc[mt][2][reg] + bjc + r*acc[mt][3][reg]);
        float ho = bf2f(NE[rl + 8][j]);
        H1[rl][j] = f2bf(z*ho + (1.f - z)*cand);
      }
    }
  }
  __syncthreads();
  // ---- P4: GAT-2 t + logits for 80 rows ----
  {
    f32x4 acc[5];
    #pragma unroll
    for (int mt=0;mt<5;mt++) acc[mt] = (f32x4){0.f,0.f,0.f,0.f};
    #pragma unroll
    for (int kc=0;kc<4;kc++){
      int k0 = kc*32;
      bf16x8 bfr = *reinterpret_cast<const bf16x8*>(&Wgt[(16*w + l15)*128 + k0 + quad*8]);
      #pragma unroll
      for (int mt=0;mt<5;mt++){
        bf16x8 a = *reinterpret_cast<const bf16x8*>(&H1[16*mt + l15][k0 + quad*8]);
        acc[mt] = __builtin_amdgcn_mfma_f32_16x16x32_bf16(a, bfr, acc[mt], 0,0,0);
      }
    }
    int c = 16*w + l15;
    float bgc = bg[c], agc = ag[c];
    float lp[5][4];
    #pragma unroll
    for (int mt=0;mt<5;mt++)
      #pragma unroll
      for (int reg=0;reg<4;reg++){
        float t = ftanh(acc[mt][reg] + bgc);
        T[16*mt + quad*4 + reg][c] = f2bf(t);
        lp[mt][reg] = t * agc;
      }
    #pragma unroll
    for (int mt=0;mt<5;mt++)
      #pragma unroll
      for (int reg=0;reg<4;reg++){
        lp[mt][reg] += __shfl_xor(lp[mt][reg], 1);
        lp[mt][reg] += __shfl_xor(lp[mt][reg], 2);
        lp[mt][reg] += __shfl_xor(lp[mt][reg], 4);
        lp[mt][reg] += __shfl_xor(lp[mt][reg], 8);
      }
    if (l15 == 0){
      #pragma unroll
      for (int mt=0;mt<5;mt++)
        #pragma unroll
        for (int reg=0;reg<4;reg++)
          Lp[w][16*mt + quad*4 + reg] = lp[mt][reg];
    }
  }
  __syncthreads();
  if (tid < 80){
    float s = 0.f;
    #pragma unroll
    for (int i=0;i<8;i++) s += Lp[i][tid];
    Ls[tid] = s;
  }
  __syncthreads();
  // ---- P5: msg2 + x2 for 64 owned -> X[0..64) ----
  if (tid < 256){
    int vl = tid >> 2, seg = tid & 3;
    int vg = (b<<10) + n0 + vl;
    int li[16]; float at[16];
    float m = -1e30f;
    #pragma unroll
    for (int d=0; d<16; d++){
      int a = adj[vg*16 + d];
      li[d] = (a - n0 + 8) & 1023;
      m = fmaxf(m, Ls[li[d]]);
    }
    float s = 0.f;
    #pragma unroll
    for (int d=0; d<16; d++){ at[d] = __expf(Ls[li[d]] - m); s += at[d]; }
    float inv = frcp(s);
    #pragma unroll
    for (int d=0; d<16; d++) at[d] *= inv;
    #pragma unroll
    for (int c8=0; c8<4; c8++){
      int c = seg*32 + c8*8;
      float acc8[8] = {0,0,0,0,0,0,0,0};
      #pragma unroll 4
      for (int d=0; d<16; d++){
        bf16x8 tv = *reinterpret_cast<const bf16x8*>(&T[li[d]][c]);
        float a = at[d];
        #pragma unroll
        for (int q=0;q<8;q++) acc8[q] += a * bf2f(tv[q]);
      }
      bf16x8 nv = *reinterpret_cast<const bf16x8*>(&NE[vl + 16][c]);
      bf16x8 xv;
      #pragma unroll
      for (int q=0;q<8;q++) xv[q] = f2bf(ftanh(acc8[q] + bf2f(nv[q])));
      *reinterpret_cast<bf16x8*>(&X[vl][c]) = xv;
    }
  }
  __syncthreads();
  // ---- P6: GRU-2 for 64 owned ----
  {
    f32x4 acc[4][4];
    #pragma unroll
    for (int mt=0;mt<4;mt++)
      #pragma unroll
      for (int g=0;g<4;g++) acc[mt][g] = (f32x4){0.f,0.f,0.f,0.f};
    for (int k8=0;k8<8;k8++){
      int k0 = k8*32;
      int gg = (k8 < 4) ? 2 : 3;
      int ncol = 16*w + l15;
      int koff = k0 + quad*8;
      bf16x8 bz = *reinterpret_cast<const bf16x8*>(&Wt[(ncol      )*256 + koff]);
      bf16x8 br = *reinterpret_cast<const bf16x8*>(&Wt[(ncol + 128)*256 + koff]);
      bf16x8 bc = *reinterpret_cast<const bf16x8*>(&Wt[(ncol + gg*128)*256 + koff]);
      #pragma unroll
      for (int mt=0;mt<4;mt++){
        bf16x8 a;
        if (k8 < 4) a = *reinterpret_cast<const bf16x8*>(&X[16*mt + l15][k0 + quad*8]);
        else        a = *reinterpret_cast<const bf16x8*>(&H1[16*mt + l15 + 8][k0 - 128 + quad*8]);
        acc[mt][0]  = __builtin_amdgcn_mfma_f32_16x16x32_bf16(a, bz, acc[mt][0], 0,0,0);
        acc[mt][1]  = __builtin_amdgcn_mfma_f32_16x16x32_bf16(a, br, acc[mt][1], 0,0,0);
        acc[mt][gg] = __builtin_amdgcn_mfma_f32_16x16x32_bf16(a, bc, acc[mt][gg], 0,0,0);
      }
    }
    __syncthreads();   // X is MFMA input above, epilogue output below
    int j = 16*w + l15;
    float bjz = bgru[j], bjr = bgru[128 + j], bjc = bgru[256 + j];
    #pragma unroll
    for (int mt=0;mt<4;mt++){
      #pragma unroll
      for (int reg=0;reg<4;reg++){
        int rl = 16*mt + quad*4 + reg;
        float z = fsig(acc[mt][0][reg] + bjz);
        float r = fsig(acc[mt][1][reg] + bjr);
        float cand = ftanh(acc[mt][2][reg] + bjc + r*acc[mt][3][reg]);
        float ho = bf2f(H1[rl + 8][j]);
        X[rl][j] = f2bf(z*ho + (1.f - z)*cand);
      }
    }
  }
  __syncthreads();
  for (int idx=tid; idx<64*16; idx+=512){
    int r = idx >> 4, c8 = idx & 15;
    *reinterpret_cast<bf16x8*>(&hout[(long)((b<<10) + n0 + r)*128 + c8*8]) =
        *reinterpret_cast<const bf16x8*>(&X[r][c8*8]);
  }
}

// Fused decoder + dest-attn + sparsemax + dual-vars, 512 threads.
__global__ __launch_bounds__(512,2) void k_decdas(const short* __restrict__ hn, const int* __restrict__ adj,
    const int* __restrict__ invadj, const short* __restrict__ Wpq, const float* __restrict__ b1,
    const float* __restrict__ W2, const float* __restrict__ b2_,
    const short* __restrict__ Wu1t, const float* __restrict__ bu1, const float* __restrict__ Wu2,
    const float* __restrict__ bu2_, float* __restrict__ norm_, float* __restrict__ dv){
  __shared__ short Hs[112][136];
  __shared__ short PQb[112][132];
  __shared__ short NSs[64][136];
  __shared__ int adjL[64][16];
  __shared__ float dvp[64][4];
  __shared__ float b1s[64], w2s[64], bu1s[64], wu2s[64];
  int tid = threadIdx.x;
  int blk = blockIdx.x;
  int b = blk >> 4;
  int n0 = (blk & 15) << 6;
  if (tid < 64){ b1s[tid] = b1[tid]; w2s[tid] = W2[tid]; bu1s[tid] = bu1[tid]; wu2s[tid] = Wu2[tid]; }
  for (int idx=tid; idx<112*16; idx+=512){
    int r = idx >> 4, c8 = idx & 15;
    int g = (b << 10) + ((n0 - 24 + r) & 1023);
    *reinterpret_cast<bf16x8*>(&Hs[r][c8*8]) =
        *reinterpret_cast<const bf16x8*>(&hn[(long)g*128 + c8*8]);
  }
  for (int idx=tid; idx<1024; idx+=512){
    int r = idx >> 4, d = idx & 15;
    int a = adj[((b<<10) + n0 + r)*16 + d];
    adjL[r][d] = (a - n0 + 24) & 1023;
  }
  __syncthreads();
  int w = tid >> 6, lane = tid & 63;
  int l15 = lane & 15, quad = lane >> 4;
  {
    f32x4 acc[7];
    #pragma unroll
    for (int mt=0;mt<7;mt++) acc[mt] = (f32x4){0.f,0.f,0.f,0.f};
    #pragma unroll
    for (int kc=0;kc<4;kc++){
      int k0 = kc*32;
      bf16x8 bfr = *reinterpret_cast<const bf16x8*>(&Wpq[(16*w + l15)*128 + k0 + quad*8]);
      #pragma unroll
      for (int mt=0;mt<7;mt++){
        bf16x8 a = *reinterpret_cast<const bf16x8*>(&Hs[16*mt + l15][k0 + quad*8]);
        acc[mt] = __builtin_amdgcn_mfma_f32_16x16x32_bf16(a, bfr, acc[mt], 0,0,0);
      }
    }
    int c = 16*w + l15;
    #pragma unroll
    for (int mt=0;mt<7;mt++)
      #pragma unroll
      for (int reg=0;reg<4;reg++)
        PQb[16*mt + quad*4 + reg][c] = f2bf(acc[mt][reg]);
  }
  for (int idx=tid; idx<64*16; idx+=512){
    int r = idx >> 4, c8 = idx & 15;
    float acc8[8] = {0,0,0,0,0,0,0,0};
    #pragma unroll 4
    for (int d=0; d<16; d++){
      bf16x8 hv = *reinterpret_cast<const bf16x8*>(&Hs[adjL[r][d]][c8*8]);
      #pragma unroll
      for (int q=0;q<8;q++) acc8[q] += bf2f(hv[q]);
    }
    bf16x8 sv;
    #pragma unroll
    for (int q=0;q<8;q++) sv[q] = f2bf(acc8[q]);
    *reinterpret_cast<bf16x8*>(&NSs[r][c8*8]) = sv;
  }
  __syncthreads();
  if (w < 4){
    f32x4 acc[4];
    #pragma unroll
    for (int mt=0;mt<4;mt++) acc[mt] = (f32x4){0.f,0.f,0.f,0.f};
    #pragma unroll
    for (int kc=0;kc<4;kc++){
      int k0 = kc*32;
      bf16x8 bfr = *reinterpret_cast<const bf16x8*>(&Wu1t[(16*w + l15)*128 + k0 + quad*8]);
      #pragma unroll
      for (int mt=0;mt<4;mt++){
        bf16x8 a = *reinterpret_cast<const bf16x8*>(&NSs[16*mt + l15][k0 + quad*8]);
        acc[mt] = __builtin_amdgcn_mfma_f32_16x16x32_bf16(a, bfr, acc[mt], 0,0,0);
      }
    }
    int n = 16*w + l15;
    float bn = bu1s[n], wn = wu2s[n];
    #pragma unroll
    for (int mt=0;mt<4;mt++){
      #pragma unroll
      for (int reg=0;reg<4;reg++){
        float p = ftanh(acc[mt][reg] + bn) * wn;
        p += __shfl_xor(p, 1);
        p += __shfl_xor(p, 2);
        p += __shfl_xor(p, 4);
        p += __shfl_xor(p, 8);
        if (l15 == 0) dvp[16*mt + quad*4 + reg][w] = p;
      }
    }
  }
  __syncthreads();
  float* nws = reinterpret_cast<float*>(&Hs[0][0]);   // [96][17]
  float b2v = b2_[0];
  for (int e = tid; e < 96*16; e += 512){
    int rr = e >> 4, d = e & 15;
    int wnode = (n0 + rr - 16) & 1023;
    int wg = (b<<10) + wnode;
    int a = adj[wg*16 + d];
    int al = (a - n0 + 24) & 1023;
    int wl = rr + 8;
    float p = 0.f;
    #pragma unroll 8
    for (int c=0;c<64;c++)
      p += ftanh(bf2f(PQb[al][c]) + bf2f(PQb[wl][64 + c]) + b1s[c]) * w2s[c];
    nws[rr*17 + d] = p + b2v;
  }
  __syncthreads();
  if (tid < 64){
    float val = dvp[tid][0]+dvp[tid][1]+dvp[tid][2]+dvp[tid][3];
    dv[(b<<10) + n0 + tid] = fmaxf(val + bu2_[0], 0.f);
  }
  float* datt = reinterpret_cast<float*>(&PQb[0][0]); // [80][17]
  if (tid < 80){
    int wnode = (n0 + tid - 8) & 1023;
    int wg = (b<<10) + wnode;
    float vals[16];
    float m = -1e30f;
    #pragma unroll
    for (int d=0; d<16; d++){
      int iv = invadj[wg*16 + d];
      int il = (iv - n0 + 16) & 1023;
      vals[d] = nws[il*17 + d];
      m = fmaxf(m, vals[d]);
    }
    float s = 0.f;
    #pragma unroll
    for (int d=0; d<16; d++){ vals[d] = __expf(vals[d]-m); s += vals[d]; }
    float inv = frcp(s);
    #pragma unroll
    for (int d=0; d<16; d++) datt[tid*17 + d] = vals[d]*inv;
  }
  __syncthreads();
  if (tid < 64){
    int vg = (b<<10) + n0 + tid;
    float z[16], s[16];
    #pragma unroll
    for (int d=0; d<16; d++){
      int al = adjL[tid][d] - 16;
      z[d] = datt[al*17 + d];
      s[d] = z[d];
    }
    #pragma unroll
    for (int k2 = 2; k2 <= 16; k2 <<= 1){
      #pragma unroll
      for (int jj = k2 >> 1; jj > 0; jj >>= 1){
        #pragma unroll
        for (int i = 0; i < 16; i++){
          int l = i ^ jj;
          if (l > i){
            bool up = ((i & k2) == 0);
            float a = s[i], bb = s[l];
            bool sw = up ? (a > bb) : (a < bb);
            if (sw){ s[i]=bb; s[l]=a; }
          }
        }
      }
    }
    float cs = 0.f, zcs = 0.f; int kz = 1;
    #pragma unroll
    for (int j=0;j<16;j++){
      float zj = s[15-j];
      cs += zj;
      if (1.f + (float)(j+1)*zj > cs){ kz = j+1; zcs = cs; }
    }
    float tau = (zcs - 1.f)/(float)kz;
    #pragma unroll
    for (int d=0; d<16; d++) norm_[(long)vg*16 + d] = fmaxf(z[d]-tau, 0.f);
  }
}

// Fused flow solver + dual cost + dual demand + final output.
__global__ __launch_bounds__(1024) void k_flowfin(const float* __restrict__ norm_,
    const float* __restrict__ dem, const int* __restrict__ invadj, const float* __restrict__ dv,
    float* __restrict__ out){
  __shared__ float nrmS[V*17];
  __shared__ float sbuf[2][V];
  __shared__ float r1[16], r2[16], r3[16];
  int b = blockIdx.x, v = threadIdx.x;
  int gv = (b<<10) + v;
  {
    const float4* src = reinterpret_cast<const float4*>(&norm_[(long)gv*16]);
    #pragma unroll
    for (int q4=0; q4<4; q4++){
      float4 x = src[q4];
      nrmS[v*17 + q4*4+0] = x.x; nrmS[v*17 + q4*4+1] = x.y;
      nrmS[v*17 + q4*4+2] = x.z; nrmS[v*17 + q4*4+3] = x.w;
    }
  }
  int iv[16];
  #pragma unroll
  for (int d4=0; d4<4; d4++){
    int4 i4 = reinterpret_cast<const int4*>(&invadj[(long)gv*16])[d4];
    iv[d4*4+0]=i4.x; iv[d4*4+1]=i4.y; iv[d4*4+2]=i4.z; iv[d4*4+3]=i4.w;
  }
  float dm = dem[gv];
  sbuf[0][v] = 0.f;
  __syncthreads();
  float nrg[16]; float nr2 = 0.f;
  #pragma unroll
  for (int d=0; d<16; d++){
    nrg[d] = nrmS[iv[d]*17 + d];
    float nv = nrmS[v*17 + d];
    nr2 += nv*nv;
  }
  int p = 0;
  float s = 0.f;
  for (int it=0; it<10; it++){
    float inflow = 0.f;
    #pragma unroll
    for (int d=0; d<16; d++) inflow += nrg[d]*sbuf[p][iv[d]];
    s = fmaxf(inflow - dm, 0.f);
    sbuf[1-p][v] = s;
    p ^= 1;
    __syncthreads();
  }
  float partF = nr2 * s * s;
  float dvv = dv[gv];
  float f = 0.f, vel = 0.f;
  #pragma unroll
  for (int it=0; it<10; it++){
    float g = 2.f*f + dvv;
    vel = 0.9f*vel - 0.01f*g;
    f = fmaxf(f + vel, 0.f);
  }
  float partD = f*f + dvv*f;
  float partDD = dvv * dm;
  #pragma unroll
  for (int off=32; off>0; off>>=1){
    partF  += __shfl_down(partF, off);
    partD  += __shfl_down(partD, off);
    partDD += __shfl_down(partDD, off);
  }
  if ((v & 63) == 0){ r1[v>>6] = partF; r2[v>>6] = partD; r3[v>>6] = partDD; }
  __syncthreads();
  if (v == 0){
    float sf = 0.f, sd = 0.f, sdd = 0.f;
    #pragma unroll
    for (int i=0;i<16;i++){ sf += r1[i]; sd += r2[i]; sdd += r3[i]; }
    out[b] = sf - (16.f*sd - sdd);
  }
}

extern "C" void kernel_launch(void* const* d_in, const int* in_sizes, int n_in,
                              void* d_out, int out_size, void* d_ws, size_t ws_size,
                              hipStream_t stream){
  (void)in_sizes; (void)n_in; (void)out_size; (void)ws_size;
  const float* demands = (const float*)d_in[0];
  const float* nf      = (const float*)d_in[1];
  const float* emb     = (const float*)d_in[4];
  const float* Wenc    = (const float*)d_in[5];
  const float* benc    = (const float*)d_in[6];
  const float* Wgat    = (const float*)d_in[7];
  const float* bgat    = (const float*)d_in[8];
  const float* agat    = (const float*)d_in[9];
  const float* Wgx     = (const float*)d_in[10];
  const float* Wgh     = (const float*)d_in[11];
  const float* bgru    = (const float*)d_in[12];
  const float* Wd1     = (const float*)d_in[13];
  const float* bd1     = (const float*)d_in[14];
  const float* Wd2     = (const float*)d_in[15];
  const float* bd2     = (const float*)d_in[16];
  const float* Wu1     = (const float*)d_in[17];
  const float* bu1     = (const float*)d_in[18];
  const float* Wu2     = (const float*)d_in[19];
  const float* bu2     = (const float*)d_in[20];
  const int* adj       = (const int*)d_in[21];
  const int* invadj    = (const int*)d_in[22];

  float* ws    = (float*)d_ws;
  short* hnB   = (short*)(ws + OFF_HNB);
  float* nrm   = ws + OFF_NORM;
  float* dv    = ws + OFF_DV;
  short* wt    = (short*)(ws + OFF_WT);
  short* wtg   = (short*)(ws + OFF_WTG);
  short* wpq   = (short*)(ws + OFF_WPQ);
  short* wu1t  = (short*)(ws + OFF_WU1T);
  short* wenct = (short*)(ws + OFF_WENCT);

  k_pre<<<704, 256, 0, stream>>>(Wgx, Wgh, Wgat, Wd1, Wu1, Wenc, wt, wtg, wpq, wu1t, wenct);
  k_mega<<<BV/64, 512, 0, stream>>>(emb, nf, wenct, benc, adj, wtg, bgat, agat, wt, bgru, hnB);
  k_decdas<<<BV/64, 512, 0, stream>>>(hnB, adj, invadj, wpq, bd1, Wd2, bd2,
                                      wu1t, bu1, Wu2, bu2, nrm, dv);
  k_flowfin<<<B, 1024, 0, stream>>>(nrm, demands, invadj, dv, (float*)d_out);
}